// Round 2
// baseline (340.430 us; speedup 1.0000x reference)
//
#include <hip/hip_runtime.h>

// NHWC conv 3x3 stride-1 SAME: x[16,128,128,64] f32, w[3,3,64,128] f32,
// bias[128] f32 -> out[16,128,128,128] f32.
// Implicit GEMM, bf16 MFMA 16x16x32.
// Round 4: NO LDS, NO barriers. x is pre-converted to bf16 in a separate
// bandwidth-bound pass (workspace); conv kernel loads A-fragments directly
// from L1/L2 (16B per-lane loads) and B-fragments from L2-resident wt.
// Latency hidden by TLP (no barrier lockstep) + full unroll ILP.
// Round-2 LDS kernel kept as fallback for small workspace.

#define HH 128
#define WW 128
#define CIN 64
#define COUT 128

typedef __attribute__((ext_vector_type(8))) short v8s;   // 8 bf16 = 16 B
typedef __attribute__((ext_vector_type(4))) float v4f;   // MFMA C/D

#define ROW_CHUNKS 1040            // 130 px * 8 chunks(16B) per px (LDS path)
#define WS_WT     (9u * CIN * COUT * 2u)                  // 147,456 B
#define WS_FULL   (WS_WT + 16u * HH * WW * CIN * 2u)      // + 33.5 MB x_bf16

static __device__ __forceinline__ unsigned short f2bf(float f) {
    unsigned int u = __float_as_uint(f);
    unsigned int r = (u + 0x7fffu + ((u >> 16) & 1u)) >> 16;   // RNE
    return (unsigned short)r;
}

// ---- pre-pass: w[tap][ci][co] fp32 -> w_t[tap][co][ci] bf16 ----
__global__ __launch_bounds__(256) void cvt_w(const float* __restrict__ wgt,
                                             unsigned short* __restrict__ wt) {
    int idx = blockIdx.x * 256 + threadIdx.x;   // < 9*64*128 = 73728
    if (idx >= 9 * CIN * COUT) return;
    int co  = idx & (COUT - 1);
    int ci  = (idx >> 7) & (CIN - 1);
    int tap = idx >> 13;
    wt[(tap * COUT + co) * CIN + ci] = f2bf(wgt[idx]);
}

// ---- pre-pass: x fp32 -> bf16, layout unchanged [16,128,128,64] ----
__global__ __launch_bounds__(256) void cvt_x(const float* __restrict__ x,
                                             unsigned short* __restrict__ xb) {
    size_t idx = (size_t)blockIdx.x * 256 + threadIdx.x;  // 8 elems / thread
    const float4* xp = (const float4*)x;
    float4 a = xp[2 * idx];
    float4 b = xp[2 * idx + 1];
    v8s ch;
    ch[0] = (short)f2bf(a.x); ch[1] = (short)f2bf(a.y);
    ch[2] = (short)f2bf(a.z); ch[3] = (short)f2bf(a.w);
    ch[4] = (short)f2bf(b.x); ch[5] = (short)f2bf(b.y);
    ch[6] = (short)f2bf(b.z); ch[7] = (short)f2bf(b.w);
    ((v8s*)xb)[idx] = ch;
}

// ---- main: no-LDS direct-fragment implicit-GEMM MFMA conv ----
// Block = one image row (128 px x 128 co), 4 waves in 2x2, each wave 64x64.
__global__ __launch_bounds__(256, 3) void conv_mfma_direct(
    const unsigned short* __restrict__ xb,   // bf16 [16,128,128,64]
    const unsigned short* __restrict__ wt,   // bf16 [9,128,64] (tap,co,ci)
    const float* __restrict__ bias,
    float* __restrict__ out) {
    // XCD-aware remap: consecutive h on same XCD (2 images per XCD)
    int bid = blockIdx.x;                   // 0..2047
    int logical = ((bid & 7) << 8) | (bid >> 3);
    int h = logical & (HH - 1);
    int n = logical >> 7;

    int tid  = threadIdx.x;
    int lane = tid & 63;
    int wid  = tid >> 6;           // 0..3
    int wi = wid >> 1;             // pixel half (0/1)
    int wj = wid & 1;              // cout half (0/1)
    int l15  = lane & 15;
    int quad = lane >> 4;
    int pixelL = wi * 64 + l15;    // lane's base pixel (m index)

    v4f acc[4][4];
    #pragma unroll
    for (int i = 0; i < 4; ++i)
        #pragma unroll
        for (int j = 0; j < 4; ++j) acc[i][j] = (v4f)0.f;

    #pragma unroll
    for (int dh = 0; dh < 3; ++dh) {
        int ih = h + dh - 1;
        if (ih < 0 || ih >= HH) continue;          // block-uniform
        const unsigned short* rp = xb + ((size_t)(n * HH + ih)) * WW * CIN;
        #pragma unroll
        for (int dw = 0; dw < 3; ++dw) {
            const unsigned short* wtap = wt + (dh * 3 + dw) * COUT * CIN;
            #pragma unroll
            for (int kc = 0; kc < 2; ++kc) {
                v8s bfrag[4];
                #pragma unroll
                for (int tt = 0; tt < 4; ++tt) {
                    int co = wj * 64 + tt * 16 + l15;
                    bfrag[tt] = *(const v8s*)(wtap + co * CIN + kc * 32 + quad * 8);
                }
                v8s afrag[4];
                #pragma unroll
                for (int tt = 0; tt < 4; ++tt) {
                    int pl = pixelL + tt * 16 + dw;   // 0..129 (pl-1 = in px)
                    const v8s* ap = (const v8s*)(rp + (size_t)(pl - 1) * CIN +
                                                 kc * 32 + quad * 8);
                    // only (tt==0,dw==0) can hit pl==0 and (tt==3,dw==2)
                    // can hit pl==129 -> predicate exactly those (folded
                    // per unrolled iteration, zero cost elsewhere)
                    if ((tt == 0 && dw == 0) || (tt == 3 && dw == 2)) {
                        afrag[tt] = (pl >= 1 && pl <= 128) ? *ap : (v8s)(short)0;
                    } else {
                        afrag[tt] = *ap;
                    }
                }
                #pragma unroll
                for (int ti = 0; ti < 4; ++ti)
                    #pragma unroll
                    for (int tj = 0; tj < 4; ++tj)
                        acc[ti][tj] = __builtin_amdgcn_mfma_f32_16x16x32_bf16(
                            afrag[ti], bfrag[tj], acc[ti][tj], 0, 0, 0);
            }
        }
    }

    float bv[4];
    #pragma unroll
    for (int tj = 0; tj < 4; ++tj) bv[tj] = bias[wj * 64 + tj * 16 + l15];

    float* orow = out + ((size_t)(n * HH + h)) * WW * COUT;
    #pragma unroll
    for (int ti = 0; ti < 4; ++ti) {
        #pragma unroll
        for (int r = 0; r < 4; ++r) {
            int p = wi * 64 + ti * 16 + quad * 4 + r;    // C/D: row=quad*4+reg
            float* op = orow + (size_t)p * COUT + wj * 64 + l15;  // col=lane&15
            #pragma unroll
            for (int tj = 0; tj < 4; ++tj)
                op[tj * 16] = acc[ti][tj][r] + bv[tj];
        }
    }
}

// ---- fallback: round-2 LDS-staged kernel (f32 input), proven 125 us ----
__global__ __launch_bounds__(256, 3) void conv_mfma_lds(
    const float* __restrict__ x,            // fp32 [16,128,128,64]
    const unsigned short* __restrict__ wt,  // bf16 [9,128,64] (tap,co,ci)
    const float* __restrict__ bias,
    float* __restrict__ out) {
    __shared__ v8s smem[3 * ROW_CHUNKS];    // 49,920 B

    int bid = blockIdx.x;                   // 0..2047
    int logical = ((bid & 7) << 8) | (bid >> 3);
    int h = logical & (HH - 1);
    int n = logical >> 7;

    int tid  = threadIdx.x;
    int lane = tid & 63;
    int wid  = tid >> 6;
    int wi = wid >> 1;
    int wj = wid & 1;
    int l15  = lane & 15;
    int quad = lane >> 4;
    int pixelL = wi * 64 + l15;

    if (tid < 48) {
        int row = tid >> 4, k = tid & 15;
        int c = (k < 8) ? k : (1024 + k);
        smem[row * ROW_CHUNKS + c] = (v8s)(short)0;
    }

    #pragma unroll
    for (int dh = 0; dh < 3; ++dh) {
        int ih = h + dh - 1;
        if (ih < 0 || ih >= HH) continue;
        const float* rowf = x + ((size_t)(n * HH + ih)) * WW * CIN;
        #pragma unroll
        for (int k = 0; k < 4; ++k) {
            int c = 8 + tid + (k << 8);
            const float* p = rowf + (size_t)(c - 8) * 8;
            float4 a = *(const float4*)p;
            float4 b = *(const float4*)(p + 4);
            v8s ch;
            ch[0] = (short)f2bf(a.x); ch[1] = (short)f2bf(a.y);
            ch[2] = (short)f2bf(a.z); ch[3] = (short)f2bf(a.w);
            ch[4] = (short)f2bf(b.x); ch[5] = (short)f2bf(b.y);
            ch[6] = (short)f2bf(b.z); ch[7] = (short)f2bf(b.w);
            int cp = c ^ ((c >> 3) & 7);
            smem[dh * ROW_CHUNKS + cp] = ch;
        }
    }
    __syncthreads();

    v4f acc[4][4];
    #pragma unroll
    for (int i = 0; i < 4; ++i)
        #pragma unroll
        for (int j = 0; j < 4; ++j) acc[i][j] = (v4f)0.f;

    #pragma unroll
    for (int dh = 0; dh < 3; ++dh) {
        int ih = h + dh - 1;
        if (ih < 0 || ih >= HH) continue;
        const v8s* srow = smem + dh * ROW_CHUNKS;
        #pragma unroll
        for (int dw = 0; dw < 3; ++dw) {
            const unsigned short* wtap = wt + (dh * 3 + dw) * COUT * CIN;
            #pragma unroll
            for (int kc = 0; kc < 2; ++kc) {
                v8s bfrag[4];
                #pragma unroll
                for (int tt = 0; tt < 4; ++tt) {
                    int co = wj * 64 + tt * 16 + l15;
                    bfrag[tt] = *(const v8s*)(wtap + co * CIN + kc * 32 + quad * 8);
                }
                v8s afrag[4];
                #pragma unroll
                for (int tt = 0; tt < 4; ++tt) {
                    int pl = pixelL + tt * 16 + dw;
                    int c  = pl * 8 + kc * 4 + quad;
                    afrag[tt] = srow[c ^ (pl & 7)];
                }
                #pragma unroll
                for (int ti = 0; ti < 4; ++ti)
                    #pragma unroll
                    for (int tj = 0; tj < 4; ++tj)
                        acc[ti][tj] = __builtin_amdgcn_mfma_f32_16x16x32_bf16(
                            afrag[ti], bfrag[tj], acc[ti][tj], 0, 0, 0);
            }
        }
    }

    float bv[4];
    #pragma unroll
    for (int tj = 0; tj < 4; ++tj) bv[tj] = bias[wj * 64 + tj * 16 + l15];

    float* orow = out + ((size_t)(n * HH + h)) * WW * COUT;
    #pragma unroll
    for (int ti = 0; ti < 4; ++ti) {
        #pragma unroll
        for (int r = 0; r < 4; ++r) {
            int p = wi * 64 + ti * 16 + quad * 4 + r;
            float* op = orow + (size_t)p * COUT + wj * 64 + l15;
            #pragma unroll
            for (int tj = 0; tj < 4; ++tj)
                op[tj * 16] = acc[ti][tj][r] + bv[tj];
        }
    }
}

// ---- fallback (direct conv) if workspace is too small ----
__global__ __launch_bounds__(256) void conv3x3_direct(
    const float* __restrict__ x, const float* __restrict__ wgt,
    const float* __restrict__ bias, float* __restrict__ out) {
    int idx = blockIdx.x * 256 + threadIdx.x;
    int co = idx & (COUT - 1);
    int w  = (idx >> 7) & (WW - 1);
    int h  = (idx >> 14) & (HH - 1);
    int n  = idx >> 21;
    float acc = bias[co];
    #pragma unroll
    for (int kh = 0; kh < 3; ++kh) {
        int ih = h + kh - 1;
        if (ih < 0 || ih >= HH) continue;
        #pragma unroll
        for (int kw = 0; kw < 3; ++kw) {
            int iw = w + kw - 1;
            if (iw < 0 || iw >= WW) continue;
            const float* xp = x + (((size_t)(n * HH + ih) * WW + iw) * CIN);
            const float* wp = wgt + ((size_t)((kh * 3 + kw) * CIN)) * COUT + co;
            #pragma unroll 8
            for (int ci = 0; ci < CIN; ++ci)
                acc = fmaf(xp[ci], wp[(size_t)ci * COUT], acc);
        }
    }
    out[idx] = acc;
}

extern "C" void kernel_launch(void* const* d_in, const int* in_sizes, int n_in,
                              void* d_out, int out_size, void* d_ws, size_t ws_size,
                              hipStream_t stream) {
    const float* x    = (const float*)d_in[0];
    const float* wgt  = (const float*)d_in[1];
    const float* bias = (const float*)d_in[2];
    float* out = (float*)d_out;

    if (ws_size < (size_t)WS_WT) {
        int blocks = (out_size + 255) / 256;
        conv3x3_direct<<<blocks, 256, 0, stream>>>(x, wgt, bias, out);
        return;
    }

    unsigned short* wt = (unsigned short*)d_ws;
    cvt_w<<<(9 * CIN * COUT + 255) / 256, 256, 0, stream>>>(wgt, wt);

    if (ws_size >= (size_t)WS_FULL) {
        unsigned short* xbuf = wt + 9 * CIN * COUT;   // 16B-aligned offset
        int nelem8 = 16 * HH * WW * CIN / 8;          // 2,097,152 v8s chunks
        cvt_x<<<nelem8 / 256, 256, 0, stream>>>(x, xbuf);
        conv_mfma_direct<<<16 * HH, 256, 0, stream>>>(xbuf, wt, bias, out);
    } else {
        conv_mfma_lds<<<16 * HH, 256, 0, stream>>>(x, wt, bias, out);
    }
}

// Round 3
// 267.827 us; speedup vs baseline: 1.2711x; 1.2711x over previous
//
#include <hip/hip_runtime.h>

// NHWC conv 3x3 stride-1 SAME: x[16,128,128,64] f32, w[3,3,64,128] f32,
// bias[128] f32 -> out[16,128,128,128] f32.
// Implicit GEMM, bf16 MFMA 16x16x32.
// Round 5: back to the proven Round-2 structure (one image row per block,
// 3 input rows staged fp32->bf16 in LDS, xor-swizzled, zero borders,
// XCD-aware remap) but with 8 waves x (64px x 32co) tiles instead of
// 4 x (64x64): acc 64->32 VGPR, __launch_bounds__(512,6) -> 3 blocks/CU
// = 24 waves/CU resident (was 9). Pure TLP/occupancy attack; MFMA count,
// LDS layout, and HBM traffic unchanged.

#define HH 128
#define WW 128
#define CIN 64
#define COUT 128

typedef __attribute__((ext_vector_type(8))) short v8s;   // 8 bf16 = 16 B
typedef __attribute__((ext_vector_type(4))) float v4f;   // MFMA C/D

#define ROW_CHUNKS 1040            // 130 px * 8 chunks(16B) per px
#define WS_NEEDED  (9u * CIN * COUT * 2u)   // transposed bf16 weights

static __device__ __forceinline__ unsigned short f2bf(float f) {
    unsigned int u = __float_as_uint(f);
    unsigned int r = (u + 0x7fffu + ((u >> 16) & 1u)) >> 16;   // RNE
    return (unsigned short)r;
}

// ---- pre-pass: w[tap][ci][co] fp32 -> w_t[tap][co][ci] bf16 ----
__global__ __launch_bounds__(256) void cvt_w(const float* __restrict__ wgt,
                                             unsigned short* __restrict__ wt) {
    int idx = blockIdx.x * 256 + threadIdx.x;   // < 9*64*128 = 73728
    if (idx >= 9 * CIN * COUT) return;
    int co  = idx & (COUT - 1);
    int ci  = (idx >> 7) & (CIN - 1);
    int tap = idx >> 13;
    wt[(tap * COUT + co) * CIN + ci] = f2bf(wgt[idx]);
}

// ---- main: implicit-GEMM MFMA conv, 8 waves, LDS row staging ----
__global__ __launch_bounds__(512, 6) void conv_mfma(
    const float* __restrict__ x,            // fp32 [16,128,128,64]
    const unsigned short* __restrict__ wt,  // bf16 [9,128,64] (tap,co,ci)
    const float* __restrict__ bias,
    float* __restrict__ out) {
    __shared__ v8s smem[3 * ROW_CHUNKS];    // 49,920 B

    // XCD-aware remap: consecutive h on same XCD (blockIdx%8 ~ XCD id)
    int bid = blockIdx.x;                   // 0..2047
    int logical = ((bid & 7) << 8) | (bid >> 3);
    int h = logical & (HH - 1);
    int n = logical >> 7;

    int tid  = threadIdx.x;
    int lane = tid & 63;
    int wid  = tid >> 6;           // 0..7
    int wi = wid >> 2;             // pixel half (0/1)
    int wj = wid & 3;              // cout quarter (0..3)
    int l15  = lane & 15;
    int quad = lane >> 4;
    int pixelL = wi * 64 + l15;    // lane's base pixel (m index)

    // ---- zero the 1-px borders (chunks 0..7 and 1032..1039 of each row) ----
    if (tid < 48) {
        int row = tid >> 4, k = tid & 15;
        int c = (k < 8) ? k : (1024 + k);          // 0..7 or 1032..1039
        smem[row * ROW_CHUNKS + c] = (v8s)(short)0;
    }

    // ---- stage valid rows: fp32 global -> bf16 LDS (swizzled) ----
    #pragma unroll
    for (int dh = 0; dh < 3; ++dh) {
        int ih = h + dh - 1;
        if (ih < 0 || ih >= HH) continue;          // block-uniform
        const float* rowf = x + ((size_t)(n * HH + ih)) * WW * CIN;
        #pragma unroll
        for (int k = 0; k < 2; ++k) {
            int c = 8 + tid + (k << 9);            // data chunk 8..1031
            const float* p = rowf + (size_t)(c - 8) * 8;
            float4 a = *(const float4*)p;
            float4 b = *(const float4*)(p + 4);
            v8s ch;
            ch[0] = (short)f2bf(a.x); ch[1] = (short)f2bf(a.y);
            ch[2] = (short)f2bf(a.z); ch[3] = (short)f2bf(a.w);
            ch[4] = (short)f2bf(b.x); ch[5] = (short)f2bf(b.y);
            ch[6] = (short)f2bf(b.z); ch[7] = (short)f2bf(b.w);
            int cp = c ^ ((c >> 3) & 7);           // xor-swizzle within px-group
            smem[dh * ROW_CHUNKS + cp] = ch;
        }
    }
    __syncthreads();

    v4f acc[4][2];
    #pragma unroll
    for (int i = 0; i < 4; ++i)
        #pragma unroll
        for (int j = 0; j < 2; ++j) acc[i][j] = (v4f)0.f;

    #pragma unroll
    for (int dh = 0; dh < 3; ++dh) {
        int ih = h + dh - 1;
        if (ih < 0 || ih >= HH) continue;          // block-uniform
        const v8s* srow = smem + dh * ROW_CHUNKS;
        #pragma unroll
        for (int dw = 0; dw < 3; ++dw) {
            const unsigned short* wtap = wt + (dh * 3 + dw) * COUT * CIN;
            #pragma unroll
            for (int kc = 0; kc < 2; ++kc) {
                v8s bfrag[2];
                #pragma unroll
                for (int tt = 0; tt < 2; ++tt) {
                    int co = wj * 32 + tt * 16 + l15;
                    bfrag[tt] = *(const v8s*)(wtap + co * CIN + kc * 32 + quad * 8);
                }
                v8s afrag[4];
                #pragma unroll
                for (int tt = 0; tt < 4; ++tt) {
                    int pl = pixelL + tt * 16 + dw;     // 0..129, borders are 0
                    int c  = pl * 8 + kc * 4 + quad;
                    afrag[tt] = srow[c ^ (pl & 7)];
                }
                #pragma unroll
                for (int ti = 0; ti < 4; ++ti)
                    #pragma unroll
                    for (int tj = 0; tj < 2; ++tj)
                        acc[ti][tj] = __builtin_amdgcn_mfma_f32_16x16x32_bf16(
                            afrag[ti], bfrag[tj], acc[ti][tj], 0, 0, 0);
            }
        }
    }

    float bv[2];
    #pragma unroll
    for (int tj = 0; tj < 2; ++tj) bv[tj] = bias[wj * 32 + tj * 16 + l15];

    float* orow = out + ((size_t)(n * HH + h)) * WW * COUT;
    #pragma unroll
    for (int ti = 0; ti < 4; ++ti) {
        #pragma unroll
        for (int r = 0; r < 4; ++r) {
            int p = wi * 64 + ti * 16 + quad * 4 + r;    // C/D: row=quad*4+reg
            float* op = orow + (size_t)p * COUT + wj * 32 + l15;  // col=lane&15
            #pragma unroll
            for (int tj = 0; tj < 2; ++tj)
                op[tj * 16] = acc[ti][tj][r] + bv[tj];
        }
    }
}

// ---- fallback (direct conv) if workspace is too small ----
__global__ __launch_bounds__(256) void conv3x3_direct(
    const float* __restrict__ x, const float* __restrict__ wgt,
    const float* __restrict__ bias, float* __restrict__ out) {
    int idx = blockIdx.x * 256 + threadIdx.x;
    int co = idx & (COUT - 1);
    int w  = (idx >> 7) & (WW - 1);
    int h  = (idx >> 14) & (HH - 1);
    int n  = idx >> 21;
    float acc = bias[co];
    #pragma unroll
    for (int kh = 0; kh < 3; ++kh) {
        int ih = h + kh - 1;
        if (ih < 0 || ih >= HH) continue;
        #pragma unroll
        for (int kw = 0; kw < 3; ++kw) {
            int iw = w + kw - 1;
            if (iw < 0 || iw >= WW) continue;
            const float* xp = x + (((size_t)(n * HH + ih) * WW + iw) * CIN);
            const float* wp = wgt + ((size_t)((kh * 3 + kw) * CIN)) * COUT + co;
            #pragma unroll 8
            for (int ci = 0; ci < CIN; ++ci)
                acc = fmaf(xp[ci], wp[(size_t)ci * COUT], acc);
        }
    }
    out[idx] = acc;
}

extern "C" void kernel_launch(void* const* d_in, const int* in_sizes, int n_in,
                              void* d_out, int out_size, void* d_ws, size_t ws_size,
                              hipStream_t stream) {
    const float* x    = (const float*)d_in[0];
    const float* wgt  = (const float*)d_in[1];
    const float* bias = (const float*)d_in[2];
    float* out = (float*)d_out;

    if (ws_size < (size_t)WS_NEEDED) {
        int blocks = (out_size + 255) / 256;
        conv3x3_direct<<<blocks, 256, 0, stream>>>(x, wgt, bias, out);
        return;
    }

    unsigned short* wt = (unsigned short*)d_ws;
    cvt_w<<<(9 * CIN * COUT + 255) / 256, 256, 0, stream>>>(wgt, wt);
    conv_mfma<<<16 * HH, 512, 0, stream>>>(x, wt, bias, out);
}

// Round 4
// 266.152 us; speedup vs baseline: 1.2791x; 1.0063x over previous
//
#include <hip/hip_runtime.h>

// NHWC conv 3x3 stride-1 SAME: x[16,128,128,64] f32, w[3,3,64,128] f32,
// bias[128] f32 -> out[16,128,128,128] f32.
// Implicit GEMM, bf16 MFMA 16x16x32.
// Round 6: R2's proven per-wave shape (64x64 tile, 288 MFMA/wave, LDS-staged
// A with xor swizzle, B from L2, 256B write segments) kept bit-identical.
// Aggregation changed only: block = 2 output rows, 8 waves (0-3 -> row h0,
// 4-7 -> row h0+1), 4 input rows staged in 66.5KB LDS. 2 blocks/CU = 16
// waves/CU (was 9), launch_bounds(512,4) -> 128-VGPR cap (was 84).
// Staging amortized: 2 input rows per output row (was 3).

#define HH 128
#define WW 128
#define CIN 64
#define COUT 128

typedef __attribute__((ext_vector_type(8))) short v8s;   // 8 bf16 = 16 B
typedef __attribute__((ext_vector_type(4))) float v4f;   // MFMA C/D

#define ROW_CHUNKS 1040            // 130 px * 8 chunks(16B) per px
#define WS_NEEDED  (9u * CIN * COUT * 2u)   // transposed bf16 weights

static __device__ __forceinline__ unsigned short f2bf(float f) {
    unsigned int u = __float_as_uint(f);
    unsigned int r = (u + 0x7fffu + ((u >> 16) & 1u)) >> 16;   // RNE
    return (unsigned short)r;
}

// ---- pre-pass: w[tap][ci][co] fp32 -> w_t[tap][co][ci] bf16 ----
__global__ __launch_bounds__(256) void cvt_w(const float* __restrict__ wgt,
                                             unsigned short* __restrict__ wt) {
    int idx = blockIdx.x * 256 + threadIdx.x;   // < 9*64*128 = 73728
    if (idx >= 9 * CIN * COUT) return;
    int co  = idx & (COUT - 1);
    int ci  = (idx >> 7) & (CIN - 1);
    int tap = idx >> 13;
    wt[(tap * COUT + co) * CIN + ci] = f2bf(wgt[idx]);
}

// ---- main: implicit-GEMM MFMA conv, 2 rows/block, 8 waves ----
__global__ __launch_bounds__(512, 4) void conv_mfma(
    const float* __restrict__ x,            // fp32 [16,128,128,64]
    const unsigned short* __restrict__ wt,  // bf16 [9,128,64] (tap,co,ci)
    const float* __restrict__ bias,
    float* __restrict__ out) {
    __shared__ v8s smem[4 * ROW_CHUNKS];    // 4 input rows, 66,560 B

    // XCD-aware remap: 1024 blocks, 128 consecutive per XCD (2 images each)
    int bid = blockIdx.x;                   // 0..1023
    int logical = ((bid & 7) << 7) | (bid >> 3);
    int hg = logical & 63;                  // h-pair index
    int n  = logical >> 6;
    int h0 = hg * 2;

    int tid  = threadIdx.x;
    int lane = tid & 63;
    int wid  = tid >> 6;           // 0..7
    int rsel = wid >> 2;           // output row select (0/1)
    int w2   = wid & 3;            // wave-in-row, as in R2
    int wi = w2 >> 1;              // pixel half (0/1)
    int wj = w2 & 1;               // cout half (0/1)
    int l15  = lane & 15;
    int quad = lane >> 4;
    int pixelL = wi * 64 + l15;    // lane's base pixel (m index)

    // ---- zero the 1-px borders (chunks 0..7 / 1032..1039 of each slot) ----
    if (tid < 64) {
        int slot = tid >> 4, k = tid & 15;
        int c = (k < 8) ? k : (1024 + k);          // 0..7 or 1032..1039
        smem[slot * ROW_CHUNKS + c] = (v8s)(short)0;
    }

    // ---- stage 4 input rows h0-1..h0+2: fp32 -> bf16 LDS (swizzled) ----
    #pragma unroll
    for (int s = 0; s < 4; ++s) {
        int ih = h0 + s - 1;
        v8s* dst = smem + s * ROW_CHUNKS;
        if (ih >= 0 && ih < HH) {                  // block-uniform
            const float* rowf = x + ((size_t)(n * HH + ih)) * WW * CIN;
            #pragma unroll
            for (int k = 0; k < 2; ++k) {
                int c = 8 + tid + (k << 9);        // data chunk 8..1031
                const float* p = rowf + (size_t)(c - 8) * 8;
                float4 a = *(const float4*)p;
                float4 b = *(const float4*)(p + 4);
                v8s ch;
                ch[0] = (short)f2bf(a.x); ch[1] = (short)f2bf(a.y);
                ch[2] = (short)f2bf(a.z); ch[3] = (short)f2bf(a.w);
                ch[4] = (short)f2bf(b.x); ch[5] = (short)f2bf(b.y);
                ch[6] = (short)f2bf(b.z); ch[7] = (short)f2bf(b.w);
                dst[c ^ ((c >> 3) & 7)] = ch;      // xor-swizzle within px
            }
        } else {
            #pragma unroll
            for (int k = 0; k < 2; ++k) {
                int c = 8 + tid + (k << 9);
                dst[c ^ ((c >> 3) & 7)] = (v8s)(short)0;
            }
        }
    }
    __syncthreads();

    v4f acc[4][4];
    #pragma unroll
    for (int i = 0; i < 4; ++i)
        #pragma unroll
        for (int j = 0; j < 4; ++j) acc[i][j] = (v4f)0.f;

    #pragma unroll
    for (int dh = 0; dh < 3; ++dh) {
        const v8s* srow = smem + (rsel + dh) * ROW_CHUNKS;
        #pragma unroll
        for (int dw = 0; dw < 3; ++dw) {
            const unsigned short* wtap = wt + (dh * 3 + dw) * COUT * CIN;
            #pragma unroll
            for (int kc = 0; kc < 2; ++kc) {
                v8s bfrag[4];
                #pragma unroll
                for (int tt = 0; tt < 4; ++tt) {
                    int co = wj * 64 + tt * 16 + l15;
                    bfrag[tt] = *(const v8s*)(wtap + co * CIN + kc * 32 + quad * 8);
                }
                v8s afrag[4];
                #pragma unroll
                for (int tt = 0; tt < 4; ++tt) {
                    int pl = pixelL + tt * 16 + dw;     // 0..129, borders are 0
                    int c  = pl * 8 + kc * 4 + quad;
                    afrag[tt] = srow[c ^ (pl & 7)];
                }
                #pragma unroll
                for (int ti = 0; ti < 4; ++ti)
                    #pragma unroll
                    for (int tj = 0; tj < 4; ++tj)
                        acc[ti][tj] = __builtin_amdgcn_mfma_f32_16x16x32_bf16(
                            afrag[ti], bfrag[tj], acc[ti][tj], 0, 0, 0);
            }
        }
    }

    float bv[4];
    #pragma unroll
    for (int tj = 0; tj < 4; ++tj) bv[tj] = bias[wj * 64 + tj * 16 + l15];

    float* orow = out + ((size_t)(n * HH + (h0 + rsel))) * WW * COUT;
    #pragma unroll
    for (int ti = 0; ti < 4; ++ti) {
        #pragma unroll
        for (int r = 0; r < 4; ++r) {
            int p = wi * 64 + ti * 16 + quad * 4 + r;    // C/D: row=quad*4+reg
            float* op = orow + (size_t)p * COUT + wj * 64 + l15;  // col=lane&15
            #pragma unroll
            for (int tj = 0; tj < 4; ++tj)
                op[tj * 16] = acc[ti][tj][r] + bv[tj];
        }
    }
}

// ---- fallback (direct conv) if workspace is too small ----
__global__ __launch_bounds__(256) void conv3x3_direct(
    const float* __restrict__ x, const float* __restrict__ wgt,
    const float* __restrict__ bias, float* __restrict__ out) {
    int idx = blockIdx.x * 256 + threadIdx.x;
    int co = idx & (COUT - 1);
    int w  = (idx >> 7) & (WW - 1);
    int h  = (idx >> 14) & (HH - 1);
    int n  = idx >> 21;
    float acc = bias[co];
    #pragma unroll
    for (int kh = 0; kh < 3; ++kh) {
        int ih = h + kh - 1;
        if (ih < 0 || ih >= HH) continue;
        #pragma unroll
        for (int kw = 0; kw < 3; ++kw) {
            int iw = w + kw - 1;
            if (iw < 0 || iw >= WW) continue;
            const float* xp = x + (((size_t)(n * HH + ih) * WW + iw) * CIN);
            const float* wp = wgt + ((size_t)((kh * 3 + kw) * CIN)) * COUT + co;
            #pragma unroll 8
            for (int ci = 0; ci < CIN; ++ci)
                acc = fmaf(xp[ci], wp[(size_t)ci * COUT], acc);
        }
    }
    out[idx] = acc;
}

extern "C" void kernel_launch(void* const* d_in, const int* in_sizes, int n_in,
                              void* d_out, int out_size, void* d_ws, size_t ws_size,
                              hipStream_t stream) {
    const float* x    = (const float*)d_in[0];
    const float* wgt  = (const float*)d_in[1];
    const float* bias = (const float*)d_in[2];
    float* out = (float*)d_out;

    if (ws_size < (size_t)WS_NEEDED) {
        int blocks = (out_size + 255) / 256;
        conv3x3_direct<<<blocks, 256, 0, stream>>>(x, wgt, bias, out);
        return;
    }

    unsigned short* wt = (unsigned short*)d_ws;
    cvt_w<<<(9 * CIN * COUT + 255) / 256, 256, 0, stream>>>(wgt, wt);
    conv_mfma<<<16 * HH / 2, 512, 0, stream>>>(x, wt, bias, out);
}

// Round 5
// 248.009 us; speedup vs baseline: 1.3726x; 1.0732x over previous
//
#include <hip/hip_runtime.h>

// NHWC conv 3x3 stride-1 SAME: x[16,128,128,64] f32, w[3,3,64,128] f32,
// bias[128] f32 -> out[16,128,128,128] f32.
// Implicit GEMM, bf16 MFMA 16x16x32.
// Round 7: R2 structure bit-identical (one row/block, 256 thr, 4 waves of
// 64x64, 3-row LDS staging w/ xor swizzle, same stores, XCD remap) EXCEPT
// the compute loop is explicitly software-pipelined: 18 static steps
// (dh,dw,kc), B-fragments (L2) prefetched one full step ahead into named
// bcur/bnxt register buffers, afrag ds_reads staggered one tile ahead.
// Invalid border rows zero-filled in LDS so the step sequence is static.
// Live set ~150 VGPR, under the (256,3) cap of 168 -> 3 waves/SIMD kept.

#define HH 128
#define WW 128
#define CIN 64
#define COUT 128

typedef __attribute__((ext_vector_type(8))) short v8s;   // 8 bf16 = 16 B
typedef __attribute__((ext_vector_type(4))) float v4f;   // MFMA C/D

#define ROW_CHUNKS 1040            // 130 px * 8 chunks(16B) per px
#define WS_NEEDED  (9u * CIN * COUT * 2u)   // transposed bf16 weights

static __device__ __forceinline__ unsigned short f2bf(float f) {
    unsigned int u = __float_as_uint(f);
    unsigned int r = (u + 0x7fffu + ((u >> 16) & 1u)) >> 16;   // RNE
    return (unsigned short)r;
}

// ---- pre-pass: w[tap][ci][co] fp32 -> w_t[tap][co][ci] bf16 ----
__global__ __launch_bounds__(256) void cvt_w(const float* __restrict__ wgt,
                                             unsigned short* __restrict__ wt) {
    int idx = blockIdx.x * 256 + threadIdx.x;   // < 9*64*128 = 73728
    if (idx >= 9 * CIN * COUT) return;
    int co  = idx & (COUT - 1);
    int ci  = (idx >> 7) & (CIN - 1);
    int tap = idx >> 13;
    wt[(tap * COUT + co) * CIN + ci] = f2bf(wgt[idx]);
}

// ---- main: implicit-GEMM MFMA conv, software-pipelined B stream ----
__global__ __launch_bounds__(256, 3) void conv_mfma(
    const float* __restrict__ x,            // fp32 [16,128,128,64]
    const unsigned short* __restrict__ wt,  // bf16 [9,128,64] (tap,co,ci)
    const float* __restrict__ bias,
    float* __restrict__ out) {
    __shared__ v8s smem[3 * ROW_CHUNKS];    // 49,920 B

    // XCD-aware remap: consecutive h on same XCD (blockIdx%8 ~ XCD id)
    int bid = blockIdx.x;                   // 0..2047
    int logical = ((bid & 7) << 8) | (bid >> 3);
    int h = logical & (HH - 1);
    int n = logical >> 7;

    int tid  = threadIdx.x;
    int lane = tid & 63;
    int wid  = tid >> 6;           // 0..3
    int wi = wid >> 1;             // pixel half (0/1)
    int wj = wid & 1;              // cout half (0/1)
    int l15  = lane & 15;
    int quad = lane >> 4;
    int pixelL = wi * 64 + l15;    // lane's base pixel (m index)

    // ---- zero the 1-px borders (chunks 0..7 and 1032..1039 of each row) ----
    if (tid < 48) {
        int row = tid >> 4, k = tid & 15;
        int c = (k < 8) ? k : (1024 + k);          // 0..7 or 1032..1039
        smem[row * ROW_CHUNKS + c] = (v8s)(short)0;
    }

    // ---- stage rows: fp32 global -> bf16 LDS (swizzled); invalid -> 0 ----
    #pragma unroll
    for (int dh = 0; dh < 3; ++dh) {
        int ih = h + dh - 1;
        v8s* dst = smem + dh * ROW_CHUNKS;
        if (ih >= 0 && ih < HH) {                  // block-uniform
            const float* rowf = x + ((size_t)(n * HH + ih)) * WW * CIN;
            #pragma unroll
            for (int k = 0; k < 4; ++k) {
                int c = 8 + tid + (k << 8);        // data chunk 8..1031
                const float* p = rowf + (size_t)(c - 8) * 8;
                float4 a = *(const float4*)p;
                float4 b = *(const float4*)(p + 4);
                v8s ch;
                ch[0] = (short)f2bf(a.x); ch[1] = (short)f2bf(a.y);
                ch[2] = (short)f2bf(a.z); ch[3] = (short)f2bf(a.w);
                ch[4] = (short)f2bf(b.x); ch[5] = (short)f2bf(b.y);
                ch[6] = (short)f2bf(b.z); ch[7] = (short)f2bf(b.w);
                dst[c ^ ((c >> 3) & 7)] = ch;      // xor-swizzle within px
            }
        } else {
            #pragma unroll
            for (int k = 0; k < 4; ++k) {
                int c = 8 + tid + (k << 8);
                dst[c ^ ((c >> 3) & 7)] = (v8s)(short)0;
            }
        }
    }
    __syncthreads();

    v4f acc[4][4];
    #pragma unroll
    for (int i = 0; i < 4; ++i)
        #pragma unroll
        for (int j = 0; j < 4; ++j) acc[i][j] = (v4f)0.f;

    // ---- 18 static steps: s -> tap = s>>1 (dh = s/6, dw = (s>>1)%3),
    //      kc = s&1.  B prefetched one step ahead. ----
    const unsigned short* wlane = wt + (wj * 64 + l15) * CIN + quad * 8;
    // per-lane A base: chunk index before swizzle, minus the (tt,dw,kc) part
    int abase = pixelL * 8 + quad;

    v8s bcur[4], bnxt[4];
    #pragma unroll
    for (int t = 0; t < 4; ++t)                   // step 0: tap 0, kc 0
        bcur[t] = *(const v8s*)(wlane + t * 16 * CIN);

    #pragma unroll
    for (int s = 0; s < 18; ++s) {
        const int tap = s >> 1;                   // compile-time per unroll
        const int dh  = tap / 3;
        const int dw  = tap % 3;
        const int kc  = s & 1;

        // issue next step's B loads first (fly under this step's MFMAs)
        if (s < 17) {
            const int tapn = (s + 1) >> 1;
            const int kcn  = (s + 1) & 1;
            const unsigned short* wp =
                wlane + tapn * (COUT * CIN) + kcn * 32;
            #pragma unroll
            for (int t = 0; t < 4; ++t)
                bnxt[t] = *(const v8s*)(wp + t * 16 * CIN);
        }

        const v8s* srow = smem + dh * ROW_CHUNKS;
        const int sw = (pixelL + dw) & 7;         // swizzle key (tt-invariant)

        // afrag staggered one tile ahead of its 4 MFMAs
        v8s a0 = srow[(abase + (0 * 16 + dw) * 8 + kc * 4) ^ sw];
        v8s a1 = srow[(abase + (1 * 16 + dw) * 8 + kc * 4) ^ sw];
        #pragma unroll
        for (int tj = 0; tj < 4; ++tj)
            acc[0][tj] = __builtin_amdgcn_mfma_f32_16x16x32_bf16(
                a0, bcur[tj], acc[0][tj], 0, 0, 0);
        v8s a2 = srow[(abase + (2 * 16 + dw) * 8 + kc * 4) ^ sw];
        #pragma unroll
        for (int tj = 0; tj < 4; ++tj)
            acc[1][tj] = __builtin_amdgcn_mfma_f32_16x16x32_bf16(
                a1, bcur[tj], acc[1][tj], 0, 0, 0);
        v8s a3 = srow[(abase + (3 * 16 + dw) * 8 + kc * 4) ^ sw];
        #pragma unroll
        for (int tj = 0; tj < 4; ++tj)
            acc[2][tj] = __builtin_amdgcn_mfma_f32_16x16x32_bf16(
                a2, bcur[tj], acc[2][tj], 0, 0, 0);
        #pragma unroll
        for (int tj = 0; tj < 4; ++tj)
            acc[3][tj] = __builtin_amdgcn_mfma_f32_16x16x32_bf16(
                a3, bcur[tj], acc[3][tj], 0, 0, 0);

        if (s < 17) {
            #pragma unroll
            for (int t = 0; t < 4; ++t) bcur[t] = bnxt[t];
        }
    }

    float bv[4];
    #pragma unroll
    for (int tj = 0; tj < 4; ++tj) bv[tj] = bias[wj * 64 + tj * 16 + l15];

    float* orow = out + ((size_t)(n * HH + h)) * WW * COUT;
    #pragma unroll
    for (int ti = 0; ti < 4; ++ti) {
        #pragma unroll
        for (int r = 0; r < 4; ++r) {
            int p = wi * 64 + ti * 16 + quad * 4 + r;    // C/D: row=quad*4+reg
            float* op = orow + (size_t)p * COUT + wj * 64 + l15;  // col=lane&15
            #pragma unroll
            for (int tj = 0; tj < 4; ++tj)
                op[tj * 16] = acc[ti][tj][r] + bv[tj];
        }
    }
}

// ---- fallback (direct conv) if workspace is too small ----
__global__ __launch_bounds__(256) void conv3x3_direct(
    const float* __restrict__ x, const float* __restrict__ wgt,
    const float* __restrict__ bias, float* __restrict__ out) {
    int idx = blockIdx.x * 256 + threadIdx.x;
    int co = idx & (COUT - 1);
    int w  = (idx >> 7) & (WW - 1);
    int h  = (idx >> 14) & (HH - 1);
    int n  = idx >> 21;
    float acc = bias[co];
    #pragma unroll
    for (int kh = 0; kh < 3; ++kh) {
        int ih = h + kh - 1;
        if (ih < 0 || ih >= HH) continue;
        #pragma unroll
        for (int kw = 0; kw < 3; ++kw) {
            int iw = w + kw - 1;
            if (iw < 0 || iw >= WW) continue;
            const float* xp = x + (((size_t)(n * HH + ih) * WW + iw) * CIN);
            const float* wp = wgt + ((size_t)((kh * 3 + kw) * CIN)) * COUT + co;
            #pragma unroll 8
            for (int ci = 0; ci < CIN; ++ci)
                acc = fmaf(xp[ci], wp[(size_t)ci * COUT], acc);
        }
    }
    out[idx] = acc;
}

extern "C" void kernel_launch(void* const* d_in, const int* in_sizes, int n_in,
                              void* d_out, int out_size, void* d_ws, size_t ws_size,
                              hipStream_t stream) {
    const float* x    = (const float*)d_in[0];
    const float* wgt  = (const float*)d_in[1];
    const float* bias = (const float*)d_in[2];
    float* out = (float*)d_out;

    if (ws_size < (size_t)WS_NEEDED) {
        int blocks = (out_size + 255) / 256;
        conv3x3_direct<<<blocks, 256, 0, stream>>>(x, wgt, bias, out);
        return;
    }

    unsigned short* wt = (unsigned short*)d_ws;
    cvt_w<<<(9 * CIN * COUT + 255) / 256, 256, 0, stream>>>(wgt, wt);
    conv_mfma<<<16 * HH, 256, 0, stream>>>(x, wt, bias, out);
}

// Round 6
// 212.303 us; speedup vs baseline: 1.6035x; 1.1682x over previous
//
#include <hip/hip_runtime.h>

// NHWC conv 3x3 stride-1 SAME: x[16,128,128,64] f32, w[3,3,64,128] f32,
// bias[128] f32 -> out[16,128,128,128] f32.
// Implicit GEMM, bf16 MFMA 16x16x32.
// Round 8: R7 kept bit-identical (one row/block, 256 thr, 3-row LDS staging
// w/ xor swizzle + zero-filled invalid rows, 18 static steps, XCD remap,
// same stores) EXCEPT the B stream:
//  - waves reshaped 64x64 -> 128px x 32co: kills the 2x B duplication
//    (wi-paired waves used to load identical bfrags); per-wave B loads 72->36
//  - weight layout [tap][kc][co][ci32]: each bfrag load covers a contiguous
//    1KB window (full cacheline utilization, was 50%)
//  - true 2-step B lookahead via statically-indexed bb[3][2] rotation
//    (~160cy MFMA cover vs ~225cy L2 latency), first 2 steps issued before
//    the staging barrier.

#define HH 128
#define WW 128
#define CIN 64
#define COUT 128

typedef __attribute__((ext_vector_type(8))) short v8s;   // 8 bf16 = 16 B
typedef __attribute__((ext_vector_type(4))) float v4f;   // MFMA C/D

#define ROW_CHUNKS 1040            // 130 px * 8 chunks(16B) per px
#define WS_NEEDED  (9u * CIN * COUT * 2u)   // transposed bf16 weights

static __device__ __forceinline__ unsigned short f2bf(float f) {
    unsigned int u = __float_as_uint(f);
    unsigned int r = (u + 0x7fffu + ((u >> 16) & 1u)) >> 16;   // RNE
    return (unsigned short)r;
}

// ---- pre-pass: w[tap][ci][co] fp32 -> wt2[tap][kc][co][ci'] bf16 ----
// ci = kc*32 + ci'; per (tap,kc) a 128co x 32ci' panel, co-major.
__global__ __launch_bounds__(256) void cvt_w(const float* __restrict__ wgt,
                                             unsigned short* __restrict__ wt) {
    int idx = blockIdx.x * 256 + threadIdx.x;   // < 9*64*128 = 73728
    if (idx >= 9 * CIN * COUT) return;
    int co  = idx & (COUT - 1);
    int ci  = (idx >> 7) & (CIN - 1);
    int tap = idx >> 13;
    int kc  = ci >> 5;
    int cl  = ci & 31;
    wt[((tap * 2 + kc) * COUT + co) * 32 + cl] = f2bf(wgt[idx]);
}

// ---- main: implicit-GEMM MFMA conv, deduped + 2-deep-prefetched B ----
__global__ __launch_bounds__(256, 3) void conv_mfma(
    const float* __restrict__ x,            // fp32 [16,128,128,64]
    const unsigned short* __restrict__ wt,  // bf16 [9][2][128][32]
    const float* __restrict__ bias,
    float* __restrict__ out) {
    __shared__ v8s smem[3 * ROW_CHUNKS];    // 49,920 B

    // XCD-aware remap: consecutive h on same XCD (blockIdx%8 ~ XCD id)
    int bid = blockIdx.x;                   // 0..2047
    int logical = ((bid & 7) << 8) | (bid >> 3);
    int h = logical & (HH - 1);
    int n = logical >> 7;

    int tid  = threadIdx.x;
    int lane = tid & 63;
    int wid  = tid >> 6;           // 0..3 = cout quarter
    int l15  = lane & 15;
    int quad = lane >> 4;

    // ---- zero the 1-px borders (chunks 0..7 and 1032..1039 of each row) ----
    if (tid < 48) {
        int row = tid >> 4, k = tid & 15;
        int c = (k < 8) ? k : (1024 + k);          // 0..7 or 1032..1039
        smem[row * ROW_CHUNKS + c] = (v8s)(short)0;
    }

    // ---- stage rows: fp32 global -> bf16 LDS (swizzled); invalid -> 0 ----
    #pragma unroll
    for (int dh = 0; dh < 3; ++dh) {
        int ih = h + dh - 1;
        v8s* dst = smem + dh * ROW_CHUNKS;
        if (ih >= 0 && ih < HH) {                  // block-uniform
            const float* rowf = x + ((size_t)(n * HH + ih)) * WW * CIN;
            #pragma unroll
            for (int k = 0; k < 4; ++k) {
                int c = 8 + tid + (k << 8);        // data chunk 8..1031
                const float* p = rowf + (size_t)(c - 8) * 8;
                float4 a = *(const float4*)p;
                float4 b = *(const float4*)(p + 4);
                v8s ch;
                ch[0] = (short)f2bf(a.x); ch[1] = (short)f2bf(a.y);
                ch[2] = (short)f2bf(a.z); ch[3] = (short)f2bf(a.w);
                ch[4] = (short)f2bf(b.x); ch[5] = (short)f2bf(b.y);
                ch[6] = (short)f2bf(b.z); ch[7] = (short)f2bf(b.w);
                dst[c ^ ((c >> 3) & 7)] = ch;      // xor-swizzle within px
            }
        } else {
            #pragma unroll
            for (int k = 0; k < 4; ++k) {
                int c = 8 + tid + (k << 8);
                dst[c ^ ((c >> 3) & 7)] = (v8s)(short)0;
            }
        }
    }

    // per-lane B base: co = wid*32 + tj*16 + l15, ci' slot = quad*8
    // element index = ((tap*2+kc)*128 + co)*32 + quad*8
    const unsigned short* wlane = wt + ((size_t)(wid * 32 + l15)) * 32 + quad * 8;
    // step s: tap = s>>1, kc = s&1 -> panel offset (s)*128*32 = s*4096
    // tj offset: tj*16*32 = 512

    v8s bb[3][2];                  // 2-step lookahead, statically indexed
    #pragma unroll
    for (int tj = 0; tj < 2; ++tj) {           // step 0 (tap0,kc0)
        bb[0][tj] = *(const v8s*)(wlane + 0 * 4096 + tj * 512);
        bb[1][tj] = *(const v8s*)(wlane + 1 * 4096 + tj * 512);
    }

    __syncthreads();

    v4f acc[8][2];
    #pragma unroll
    for (int i = 0; i < 8; ++i)
        #pragma unroll
        for (int j = 0; j < 2; ++j) acc[i][j] = (v4f)0.f;

    // ---- 18 static steps: s -> tap = s>>1 (dh = tap/3, dw = tap%3), kc = s&1.
    //      B prefetched two steps ahead; afrag staggered one tile ahead. ----
    #pragma unroll
    for (int s = 0; s < 18; ++s) {
        const int tap = s >> 1;
        const int dh  = tap / 3;
        const int dw  = tap % 3;
        const int kc  = s & 1;
        const int cur = s % 3;

        if (s < 16) {                          // issue step s+2's B loads
            const int nb = (s + 2) % 3;
            #pragma unroll
            for (int tj = 0; tj < 2; ++tj)
                bb[nb][tj] = *(const v8s*)(wlane + (s + 2) * 4096 + tj * 512);
        }

        const v8s* srow = smem + dh * ROW_CHUNKS;
        // pl = l15 + ti*16 + dw ; chunk c = pl*8 + kc*4 + quad ; key = pl&7
        const int pl0 = l15 + dw;
        const int sw  = pl0 & 7;               // ti-invariant swizzle key
        const int c0  = pl0 * 8 + kc * 4 + quad;

        v8s a0 = srow[(c0 + 0 * 128) ^ sw];
        v8s a1 = srow[(c0 + 1 * 128) ^ sw];
        #pragma unroll
        for (int tj = 0; tj < 2; ++tj)
            acc[0][tj] = __builtin_amdgcn_mfma_f32_16x16x32_bf16(
                a0, bb[cur][tj], acc[0][tj], 0, 0, 0);
        v8s a2 = srow[(c0 + 2 * 128) ^ sw];
        #pragma unroll
        for (int tj = 0; tj < 2; ++tj)
            acc[1][tj] = __builtin_amdgcn_mfma_f32_16x16x32_bf16(
                a1, bb[cur][tj], acc[1][tj], 0, 0, 0);
        v8s a3 = srow[(c0 + 3 * 128) ^ sw];
        #pragma unroll
        for (int tj = 0; tj < 2; ++tj)
            acc[2][tj] = __builtin_amdgcn_mfma_f32_16x16x32_bf16(
                a2, bb[cur][tj], acc[2][tj], 0, 0, 0);
        v8s a4 = srow[(c0 + 4 * 128) ^ sw];
        #pragma unroll
        for (int tj = 0; tj < 2; ++tj)
            acc[3][tj] = __builtin_amdgcn_mfma_f32_16x16x32_bf16(
                a3, bb[cur][tj], acc[3][tj], 0, 0, 0);
        v8s a5 = srow[(c0 + 5 * 128) ^ sw];
        #pragma unroll
        for (int tj = 0; tj < 2; ++tj)
            acc[4][tj] = __builtin_amdgcn_mfma_f32_16x16x32_bf16(
                a4, bb[cur][tj], acc[4][tj], 0, 0, 0);
        v8s a6 = srow[(c0 + 6 * 128) ^ sw];
        #pragma unroll
        for (int tj = 0; tj < 2; ++tj)
            acc[5][tj] = __builtin_amdgcn_mfma_f32_16x16x32_bf16(
                a5, bb[cur][tj], acc[5][tj], 0, 0, 0);
        v8s a7 = srow[(c0 + 7 * 128) ^ sw];
        #pragma unroll
        for (int tj = 0; tj < 2; ++tj)
            acc[6][tj] = __builtin_amdgcn_mfma_f32_16x16x32_bf16(
                a6, bb[cur][tj], acc[6][tj], 0, 0, 0);
        #pragma unroll
        for (int tj = 0; tj < 2; ++tj)
            acc[7][tj] = __builtin_amdgcn_mfma_f32_16x16x32_bf16(
                a7, bb[cur][tj], acc[7][tj], 0, 0, 0);
    }

    float bv[2];
    #pragma unroll
    for (int tj = 0; tj < 2; ++tj) bv[tj] = bias[wid * 32 + tj * 16 + l15];

    float* orow = out + ((size_t)(n * HH + h)) * WW * COUT;
    #pragma unroll
    for (int ti = 0; ti < 8; ++ti) {
        #pragma unroll
        for (int r = 0; r < 4; ++r) {
            int p = ti * 16 + quad * 4 + r;              // C/D: row=quad*4+reg
            float* op = orow + (size_t)p * COUT + wid * 32 + l15;  // col=lane&15
            op[0]  = acc[ti][0][r] + bv[0];
            op[16] = acc[ti][1][r] + bv[1];
        }
    }
}

// ---- fallback (direct conv) if workspace is too small ----
__global__ __launch_bounds__(256) void conv3x3_direct(
    const float* __restrict__ x, const float* __restrict__ wgt,
    const float* __restrict__ bias, float* __restrict__ out) {
    int idx = blockIdx.x * 256 + threadIdx.x;
    int co = idx & (COUT - 1);
    int w  = (idx >> 7) & (WW - 1);
    int h  = (idx >> 14) & (HH - 1);
    int n  = idx >> 21;
    float acc = bias[co];
    #pragma unroll
    for (int kh = 0; kh < 3; ++kh) {
        int ih = h + kh - 1;
        if (ih < 0 || ih >= HH) continue;
        #pragma unroll
        for (int kw = 0; kw < 3; ++kw) {
            int iw = w + kw - 1;
            if (iw < 0 || iw >= WW) continue;
            const float* xp = x + (((size_t)(n * HH + ih) * WW + iw) * CIN);
            const float* wp = wgt + ((size_t)((kh * 3 + kw) * CIN)) * COUT + co;
            #pragma unroll 8
            for (int ci = 0; ci < CIN; ++ci)
                acc = fmaf(xp[ci], wp[(size_t)ci * COUT], acc);
        }
    }
    out[idx] = acc;
}

extern "C" void kernel_launch(void* const* d_in, const int* in_sizes, int n_in,
                              void* d_out, int out_size, void* d_ws, size_t ws_size,
                              hipStream_t stream) {
    const float* x    = (const float*)d_in[0];
    const float* wgt  = (const float*)d_in[1];
    const float* bias = (const float*)d_in[2];
    float* out = (float*)d_out;

    if (ws_size < (size_t)WS_NEEDED) {
        int blocks = (out_size + 255) / 256;
        conv3x3_direct<<<blocks, 256, 0, stream>>>(x, wgt, bias, out);
        return;
    }

    unsigned short* wt = (unsigned short*)d_ws;
    cvt_w<<<(9 * CIN * COUT + 255) / 256, 256, 0, stream>>>(wgt, wt);
    conv_mfma<<<16 * HH, 256, 0, stream>>>(x, wt, bias, out);
}